// Round 3
// baseline (84419.525 us; speedup 1.0000x reference)
//
#include <hip/hip_runtime.h>
#include <stdint.h>

// BiGRU scan, H=1024. Round 4: FUSED producer/consumer single kernel.
//  - 171 blocks x 512 threads. Waves 0-3 = the known-good Round-1 scan
//    (identical poll/dot/publish, 12.9 ms standalone). Waves 4-7 = gh
//    producers: each computes the 36 Whh columns its sibling scan waves
//    consume (340 MFLOP/block, no cross-block gh sharing -> no L2
//    coherence traffic; the old 1.6 ms gh_gemm prologue is hidden).
//  - Lockstep sync: producers write token t+2 into a 4-deep LDS ring
//    before the per-step barrier; scan prefetches token t+1 after it.
//    Slot distance is always 2 mod 4 -> race-free via the existing barrier.
//  - Weight regs UNIONED: w[9][16] = Wih rows (scan) or Whh cols (producer).
//    amdgpu_waves_per_eu(2,2) pins 2 waves/SIMD (<=256 VGPR) so the
//    allocator cannot repeat Round-2's 128-VGPR spill fiasco.

#define H    1024
#define HH   1025
#define TQ   512
#define TP   4096
#define GTOT 2050     // 2 dirs * HH output elems per step
#define NBLK 171
#define NTHR 512

typedef unsigned long long ull;

__device__ __forceinline__ float sigm(float x) { return 1.f / (1.f + __expf(-x)); }
__device__ __forceinline__ float fast_tanh(float x) {
    float e = __expf(2.f * x);
    return (e - 1.f) / (e + 1.f);
}

__global__ __launch_bounds__(NTHR) __attribute__((amdgpu_waves_per_eu(2, 2)))
void fused_bigru(
    const float* __restrict__ eq, const float* __restrict__ ep,
    const float* __restrict__ fs, const float* __restrict__ fe,
    const float* __restrict__ Wih_f, const float* __restrict__ bih_f,
    const float* __restrict__ Wih_b, const float* __restrict__ bih_b,
    const float* __restrict__ Whh_f, const float* __restrict__ bhh_f,
    const float* __restrict__ Whh_b, const float* __restrict__ bhh_b,
    ull* __restrict__ comm,   // [chain p|q][slot 0|1][GTOT] tagged values
    float* __restrict__ out)  // h_q (512*2048) then h_p (4096*2048)
{
    __shared__ float xsh[2][2][1024];   // [parity][chain p=0,q=1][j]
    __shared__ float ringP[4][4][12];   // [slot][scanwave][9 used]
    __shared__ float ringQ[4][4][12];

    const int tid  = threadIdx.x;
    const int wave = tid >> 6;
    const int lane = tid & 63;
    const bool isScan = (wave < 4);
    const int sw    = isScan ? wave : (wave - 4);
    const int gbase = blockIdx.x * 12 + sw * 3;

    int dre[3], je[3];
    bool vale[3];
#pragma unroll
    for (int e = 0; e < 3; e++) {
        int g = gbase + e;
        bool v = (g < GTOT);
        int gc = v ? g : 0;
        dre[e] = gc / HH; je[e] = gc % HH; vale[e] = v;
    }

    // ---- UNIONED weight registers ----
    // scan wave:     w[r] = Wih_dir row (gate*HH+j), 1024 wide; bias9 = bih
    // producer wave: w[r] = Whh_dir row (gate*HH+j), first 1024; wtail = elem 1024; bias9 = bhh
    float w[9][16], bias9[9], wtail[9];
#pragma unroll
    for (int e = 0; e < 3; e++) {
#pragma unroll
        for (int gate = 0; gate < 3; gate++) {
            int r = e * 3 + gate;
            const float* Wx;
            const float* bx;
            size_t stride;
            if (isScan) { Wx = dre[e] ? Wih_b : Wih_f; bx = dre[e] ? bih_b : bih_f; stride = H;  }
            else        { Wx = dre[e] ? Whh_b : Whh_f; bx = dre[e] ? bhh_b : bhh_f; stride = HH; }
            const float* wr = Wx + (size_t)(gate * HH + je[e]) * stride;
#pragma unroll
            for (int i = 0; i < 4; i++) {
                float4 w4 = *(const float4*)(wr + i * 256 + lane * 4);
                w[r][i * 4 + 0] = w4.x; w[r][i * 4 + 1] = w4.y;
                w[r][i * 4 + 2] = w4.z; w[r][i * 4 + 3] = w4.w;
            }
            bias9[r] = bx[gate * HH + je[e]];
            if (isScan) wtail[r] = 0.f;      // real branch: no speculative OOB load
            else        wtail[r] = wr[1024];
        }
    }

    // ---- wave-uniform h0 offsets (scan waves) ----
    int sh0[3], sspec[3];
#pragma unroll
    for (int e = 0; e < 3; e++) {
        sh0[e]   = __builtin_amdgcn_readfirstlane(dre[e] ? (1025 + je[e]) : je[e]);
        sspec[e] = __builtin_amdgcn_readfirstlane(
                       (dre[e] && je[e] >= 1023) ? (je[e] - 1022) : 0);
    }

    auto loadH0P = [&](int tt, float h03[3]) {
#pragma unroll
        for (int e = 0; e < 3; e++)
            h03[e] = (sspec[e] == 0) ? ep[(size_t)tt * 2048 + sh0[e]]
                   : (sspec[e] == 1) ? fs[tt] : fe[tt];
    };
    auto loadH0Q = [&](int tt, float h03[3]) {
#pragma unroll
        for (int e = 0; e < 3; e++)
            h03[e] = (sspec[e] == 0) ? eq[(size_t)tt * 2048 + sh0[e]] : 0.f;
    };

    // ---- producer: compute gh row slice for one token, write LDS ring ----
    auto produce = [&](int tok, bool isQ) {
        const float* ebase = isQ ? eq : ep;
        float x[16], xt = 0.f;
        float val[9];
        int curdir = -1;
#pragma unroll
        for (int e = 0; e < 3; e++) {
            if (dre[e] != curdir) {
                curdir = dre[e];
                if (curdir == 0) {
                    const float* b = ebase + (size_t)tok * 2048;
#pragma unroll
                    for (int i = 0; i < 4; i++) {
                        float4 v4 = *(const float4*)(b + i * 256 + lane * 4);
                        x[i * 4 + 0] = v4.x; x[i * 4 + 1] = v4.y;
                        x[i * 4 + 2] = v4.z; x[i * 4 + 3] = v4.w;
                    }
                    xt = b[1024];
                } else {
                    const float* b = ebase + (size_t)tok * 2048 + 1025;
#pragma unroll
                    for (int i = 0; i < 3; i++) {
                        float4 v4 = *(const float4*)(b + i * 256 + lane * 4);
                        x[i * 4 + 0] = v4.x; x[i * 4 + 1] = v4.y;
                        x[i * 4 + 2] = v4.z; x[i * 4 + 3] = v4.w;
                    }
                    // i=3 sub-block: k = 768 + 4*lane + m; lane 63's m=3 is
                    // k=1023 -> fs (p) / 0 (q); clamp its addr to stay in-bounds.
                    x[12] = b[768 + lane * 4 + 0];
                    x[13] = b[768 + lane * 4 + 1];
                    x[14] = b[768 + lane * 4 + 2];
                    int o15 = (lane == 63) ? 0 : (768 + lane * 4 + 3);
                    float v15 = b[o15];
                    float f1023 = isQ ? 0.f : fs[tok];
                    x[15] = (lane == 63) ? f1023 : v15;
                    xt    = isQ ? 0.f : fe[tok];
                }
            }
#pragma unroll
            for (int gate = 0; gate < 3; gate++) {
                int r = e * 3 + gate;
                float s = 0.f;
#pragma unroll
                for (int i = 0; i < 16; i++) s += w[r][i] * x[i];
#pragma unroll
                for (int off = 32; off > 0; off >>= 1) s += __shfl_xor(s, off, 64);
                val[r] = s + wtail[r] * xt + bias9[r];
            }
        }
        float (*ring)[12] = isQ ? ringQ[tok & 3] : ringP[tok & 3];
        if (lane == 0) {
#pragma unroll
            for (int r = 0; r < 9; r++) ring[sw][r] = val[r];
        }
    };

    // ---- prologue: producers fill ring tokens 0,1; scan waves init carry ----
    if (!isScan) {
        produce(0, false); produce(1, false);
        produce(0, true);  produce(1, true);
    }
    __syncthreads();

    float ghcP[9], h0cP[3], ghcQ[9], h0cQ[3];
    if (isScan) {
#pragma unroll
        for (int r = 0; r < 9; r++) { ghcP[r] = ringP[0][sw][r]; ghcQ[r] = ringQ[0][sw][r]; }
        loadH0P(0, h0cP);
        loadH0Q(0, h0cQ);
    }

    ull* commP = comm;
    ull* commQ = comm + 2 * GTOT;

    for (int t = 0; t < TP; t++) {
        const bool doq = (t < TQ);
        const int par = t & 1;

        if (isScan) {
            // ================= gather y_{t-1} -> x (polls FIRST) ============
            if (t == 0) {
#pragma unroll
                for (int u = 0; u < 4; u++) {
                    int j = tid + 256 * u;
                    xsh[par][0][j] = 0.f;
                    xsh[par][1][j] = 0.f;
                }
            } else {
                const int slot = (t + 1) & 1;     // (t-1) % 2
                const unsigned tag = (unsigned)t; // y_{t-1} carries tag t
                ull* cp = commP + slot * GTOT;
                ull* cq = commQ + slot * GTOT;
                int idx[8];
#pragma unroll
                for (int u = 0; u < 4; u++) {
                    int j = tid + 256 * u;
                    idx[2 * u]     = j;                                // yf[j]
                    idx[2 * u + 1] = (j == 0) ? 1024 : (1024 + j);     // yb[j-1]
                }
                ull vp[8], vq[8];
#pragma unroll
                for (int u = 0; u < 8; u++)
                    vp[u] = __hip_atomic_load(&cp[idx[u]], __ATOMIC_RELAXED, __HIP_MEMORY_SCOPE_AGENT);
                if (doq) {
#pragma unroll
                    for (int u = 0; u < 8; u++)
                        vq[u] = __hip_atomic_load(&cq[idx[u]], __ATOMIC_RELAXED, __HIP_MEMORY_SCOPE_AGENT);
                }
                bool done = false;
                while (!done) {
                    done = true;
#pragma unroll
                    for (int u = 0; u < 8; u++) {
                        if ((unsigned)(vp[u] >> 32) != tag) {
                            done = false;
                            vp[u] = __hip_atomic_load(&cp[idx[u]], __ATOMIC_RELAXED, __HIP_MEMORY_SCOPE_AGENT);
                        }
                    }
                    if (doq) {
#pragma unroll
                        for (int u = 0; u < 8; u++) {
                            if ((unsigned)(vq[u] >> 32) != tag) {
                                done = false;
                                vq[u] = __hip_atomic_load(&cq[idx[u]], __ATOMIC_RELAXED, __HIP_MEMORY_SCOPE_AGENT);
                            }
                        }
                    }
                }
#pragma unroll
                for (int u = 0; u < 4; u++) {
                    int j = tid + 256 * u;
                    xsh[par][0][j] = __uint_as_float((unsigned)vp[2 * u]) +
                                     __uint_as_float((unsigned)vp[2 * u + 1]);
                }
                if (doq) {
#pragma unroll
                    for (int u = 0; u < 4; u++) {
                        int j = tid + 256 * u;
                        xsh[par][1][j] = __uint_as_float((unsigned)vq[2 * u]) +
                                         __uint_as_float((unsigned)vq[2 * u + 1]);
                    }
                }
            }
        } else {
            // ============ producer: token t+2 into ring slot (t+2)&3 ========
            const int tpp = t + 2;
            if (tpp < TP) produce(tpp, false);
            if (tpp < TQ) produce(tpp, true);
        }
        __syncthreads();

        if (isScan) {
            // ====== prefetch gh (LDS ring) / h0 (global) for t+1 ============
            float ghnP[9], h0nP[3], ghnQ[9], h0nQ[3];
            const bool ldn = (t + 1) < TP;
            const bool ldq = (t + 1) < TQ;
            if (ldn) {
                const int sl = (t + 1) & 3;
#pragma unroll
                for (int r = 0; r < 9; r++) ghnP[r] = ringP[sl][sw][r];
                loadH0P(t + 1, h0nP);
            }
            if (ldq) {
                const int sl = (t + 1) & 3;
#pragma unroll
                for (int r = 0; r < 9; r++) ghnQ[r] = ringQ[sl][sw][r];
                loadH0Q(t + 1, h0nQ);
            }

            // ========================= dot products =========================
            float accp[9];
            {
                float x[16];
#pragma unroll
                for (int i = 0; i < 4; i++) {
                    float4 x4 = *(const float4*)&xsh[par][0][i * 256 + lane * 4];
                    x[i * 4 + 0] = x4.x; x[i * 4 + 1] = x4.y;
                    x[i * 4 + 2] = x4.z; x[i * 4 + 3] = x4.w;
                }
#pragma unroll
                for (int r = 0; r < 9; r++) {
                    float s = 0.f;
#pragma unroll
                    for (int i = 0; i < 16; i++) s += w[r][i] * x[i];
                    accp[r] = s;
                }
            }
#pragma unroll
            for (int r = 0; r < 9; r++) {
                float v = accp[r];
#pragma unroll
                for (int off = 32; off > 0; off >>= 1) v += __shfl_xor(v, off, 64);
                accp[r] = v + bias9[r];
            }

            float accq[9];
            if (doq) {
                float x[16];
#pragma unroll
                for (int i = 0; i < 4; i++) {
                    float4 x4 = *(const float4*)&xsh[par][1][i * 256 + lane * 4];
                    x[i * 4 + 0] = x4.x; x[i * 4 + 1] = x4.y;
                    x[i * 4 + 2] = x4.z; x[i * 4 + 3] = x4.w;
                }
#pragma unroll
                for (int r = 0; r < 9; r++) {
                    float s = 0.f;
#pragma unroll
                    for (int i = 0; i < 16; i++) s += w[r][i] * x[i];
#pragma unroll
                    for (int off = 32; off > 0; off >>= 1) s += __shfl_xor(s, off, 64);
                    accq[r] = s + bias9[r];
                }
            }

            // ============ gates; publish comm FIRST, out after ==============
            const ull tagout = ((ull)(unsigned)(t + 1)) << 32;
            float yP[3], yQ[3];
#pragma unroll
            for (int e = 0; e < 3; e++) {
                float r = sigm(accp[e * 3 + 0] + ghcP[e * 3 + 0]);
                float z = sigm(accp[e * 3 + 1] + ghcP[e * 3 + 1]);
                float n = fast_tanh(accp[e * 3 + 2] + r * ghcP[e * 3 + 2]);
                yP[e] = (1.f - z) * n + z * h0cP[e];
                if (lane == 0 && vale[e]) {
                    ull pk = tagout | (ull)__float_as_uint(yP[e]);
                    __hip_atomic_store(&commP[par * GTOT + (gbase + e)], pk,
                                       __ATOMIC_RELAXED, __HIP_MEMORY_SCOPE_AGENT);
                }
            }
            if (doq) {
#pragma unroll
                for (int e = 0; e < 3; e++) {
                    float r = sigm(accq[e * 3 + 0] + ghcQ[e * 3 + 0]);
                    float z = sigm(accq[e * 3 + 1] + ghcQ[e * 3 + 1]);
                    float n = fast_tanh(accq[e * 3 + 2] + r * ghcQ[e * 3 + 2]);
                    yQ[e] = (1.f - z) * n + z * h0cQ[e];
                    if (lane == 0 && vale[e]) {
                        ull pk = tagout | (ull)__float_as_uint(yQ[e]);
                        __hip_atomic_store(&commQ[par * GTOT + (gbase + e)], pk,
                                           __ATOMIC_RELAXED, __HIP_MEMORY_SCOPE_AGENT);
                    }
                }
            }
            // out stores (off the critical path)
            if (lane == 0) {
#pragma unroll
                for (int e = 0; e < 3; e++) {
                    if (vale[e] && je[e] < H) {
                        out[(size_t)TQ * 2048 + (size_t)t * 2048 + dre[e] * H + je[e]] = yP[e];
                        if (doq)
                            out[(size_t)t * 2048 + dre[e] * H + je[e]] = yQ[e];
                    }
                }
            }

            // rotate pipeline registers
            if (ldn) {
#pragma unroll
                for (int i = 0; i < 9; i++) ghcP[i] = ghnP[i];
#pragma unroll
                for (int e = 0; e < 3; e++) h0cP[e] = h0nP[e];
            }
            if (ldq) {
#pragma unroll
                for (int i = 0; i < 9; i++) ghcQ[i] = ghnQ[i];
#pragma unroll
                for (int e = 0; e < 3; e++) h0cQ[e] = h0nQ[e];
            }
        }
    }
}

extern "C" void kernel_launch(void* const* d_in, const int* in_sizes, int n_in,
                              void* d_out, int out_size, void* d_ws, size_t ws_size,
                              hipStream_t stream) {
    const float* eq    = (const float*)d_in[0];
    const float* ep    = (const float*)d_in[1];
    const float* fs    = (const float*)d_in[2];
    const float* fe    = (const float*)d_in[3];
    const float* Wih_f = (const float*)d_in[4];
    const float* Whh_f = (const float*)d_in[5];
    const float* bih_f = (const float*)d_in[6];
    const float* bhh_f = (const float*)d_in[7];
    const float* Wih_b = (const float*)d_in[8];
    const float* Whh_b = (const float*)d_in[9];
    const float* bih_b = (const float*)d_in[10];
    const float* bhh_b = (const float*)d_in[11];
    float* out = (float*)d_out;

    ull* comm = (ull*)d_ws;
    hipMemsetAsync(comm, 0, (size_t)4 * GTOT * sizeof(ull), stream);

    fused_bigru<<<dim3(NBLK), dim3(NTHR), 0, stream>>>(
        eq, ep, fs, fe, Wih_f, bih_f, Wih_b, bih_b,
        Whh_f, bhh_f, Whh_b, bhh_b, comm, out);
}

// Round 4
// 46778.195 us; speedup vs baseline: 1.8047x; 1.8047x over previous
//
#include <hip/hip_runtime.h>
#include <stdint.h>

// BiGRU scan, H=1024. Round 5: producer/consumer fusion with PROVEN block shape.
//  - Lesson R2/R3: 512-thread blocks make the allocator target 4 waves/EU
//    (128 VGPR) and spill the 144-float weight array to scratch (31 GB HBM
//    traffic, 6x slowdown). Only 256-thread blocks preserve the Round-1
//    204-VGPR no-spill allocation. So: producers are separate 256-thr BLOCKS.
//  - 171 scan blocks (Round-1 scan, byte-level port) + 171 producer blocks.
//    Producer block b serves scan block b: holds its 36 Whh rows in regs
//    (mirror of scan's Wih layout), streams tokens, publishes gh as tagged
//    (t+1)<<32|fp32 ulls into a ring (fence-free, same protocol as y-comm).
//  - p-ring: 512 slots, producer flow-controlled by consumer comm tag
//    (stays <=511 ahead; slot overwrite needs tag >= t+2 which is published
//    only after that slot's verify). q-ring flat (TQ=512 tokens, no wrap).
//  - Co-residency: 342 blocks x 4 waves; launch_bounds(256,2) caps VGPR at
//    256 -> >=2 blocks/CU -> capacity 512 >= 342. LDS 32KB/block -> 64KB/CU.
//  - Scan gh path: 9 relaxed agent loads issued pre-barrier, tag-verified
//    AFTER publish (off critical path); producers run ~10x ahead -> first-try.

#define H     1024
#define HH    1025
#define TQ    512
#define TP    4096
#define GTOT  2050
#define NSCAN 171
#define NPROD 171
#define NTHR  256
#define RS    512            // p-ring slots (power of two)
#define RST   (NPROD * 36)   // ulls per ring slot = 6156

typedef unsigned long long ull;

__device__ __forceinline__ float sigm(float x) { return 1.f / (1.f + __expf(-x)); }
__device__ __forceinline__ float fast_tanh(float x) {
    float e = __expf(2.f * x);
    return (e - 1.f) / (e + 1.f);
}

#define ALOAD(p)     __hip_atomic_load((p), __ATOMIC_RELAXED, __HIP_MEMORY_SCOPE_AGENT)
#define ASTORE(p, v) __hip_atomic_store((p), (v), __ATOMIC_RELAXED, __HIP_MEMORY_SCOPE_AGENT)

__global__ __launch_bounds__(NTHR, 2) void fused_bigru(
    const float* __restrict__ eq, const float* __restrict__ ep,
    const float* __restrict__ fs, const float* __restrict__ fe,
    const float* __restrict__ Wih_f, const float* __restrict__ bih_f,
    const float* __restrict__ Wih_b, const float* __restrict__ bih_b,
    const float* __restrict__ Whh_f, const float* __restrict__ bhh_f,
    const float* __restrict__ Whh_b, const float* __restrict__ bhh_b,
    ull* __restrict__ ringP, ull* __restrict__ ringQ,
    ull* __restrict__ comm,   // [chain p|q][slot 0|1][GTOT] tagged y values
    float* __restrict__ out)  // h_q (512*2048) then h_p (4096*2048)
{
    __shared__ float xsh[2][2][1024];   // scan blocks: [parity][chain][j]
    __shared__ float xrawP[2048];       // producer blocks: raw h0 rows
    __shared__ float xrawQ[2048];

    const int tid  = threadIdx.x;
    const int wave = tid >> 6;
    const int lane = tid & 63;
    const bool isScan = ((int)blockIdx.x < NSCAN);
    const int cb    = isScan ? (int)blockIdx.x : ((int)blockIdx.x - NSCAN);
    const int gbase = cb * 12 + wave * 3;

    int dre[3], je[3];
    bool vale[3];
#pragma unroll
    for (int e = 0; e < 3; e++) {
        int g = gbase + e;
        bool v = (g < GTOT);
        int gc = v ? g : 0;
        dre[e] = gc / HH; je[e] = gc % HH; vale[e] = v;
    }

    // ---- role-dependent register-resident weights ----
    // scan:     w[r] = Wih row (stride 1024), wtail unused
    // producer: w[r] = Whh row (stride 1025) first 1024, wtail = elem 1024
    float w[9][16], bias9[9], wtail[9];
#pragma unroll
    for (int e = 0; e < 3; e++) {
#pragma unroll
        for (int gate = 0; gate < 3; gate++) {
            int r = e * 3 + gate;
            const float* Wx; const float* bx; size_t stride;
            if (isScan) { Wx = dre[e] ? Wih_b : Wih_f; bx = dre[e] ? bih_b : bih_f; stride = H;  }
            else        { Wx = dre[e] ? Whh_b : Whh_f; bx = dre[e] ? bhh_b : bhh_f; stride = HH; }
            const float* wr = Wx + (size_t)(gate * HH + je[e]) * stride;
#pragma unroll
            for (int i = 0; i < 4; i++) {
                float4 w4 = *(const float4*)(wr + i * 256 + lane * 4);
                w[r][i * 4 + 0] = w4.x; w[r][i * 4 + 1] = w4.y;
                w[r][i * 4 + 2] = w4.z; w[r][i * 4 + 3] = w4.w;
            }
            bias9[r] = bx[gate * HH + je[e]];
            wtail[r] = isScan ? 0.f : wr[1024];
        }
    }

    // =======================================================================
    //                             PRODUCER PATH
    // =======================================================================
    if (!isScan) {
        ull* flow0 = comm + 0 * (size_t)GTOT + (size_t)cb * 12;  // p-comm par0, g0
        ull* flow1 = comm + 1 * (size_t)GTOT + (size_t)cb * 12;  // p-comm par1, g0

        auto prodChain = [&](const float* xr, float fsv, float fev, float v9[9]) {
            float x[16], xt = 0.f;
            int curdir = -1;
#pragma unroll
            for (int e = 0; e < 3; e++) {
                if (dre[e] != curdir) {
                    curdir = dre[e];
                    if (curdir == 0) {
#pragma unroll
                        for (int i = 0; i < 4; i++) {
                            float4 x4 = *(const float4*)&xr[i * 256 + lane * 4];
                            x[i * 4 + 0] = x4.x; x[i * 4 + 1] = x4.y;
                            x[i * 4 + 2] = x4.z; x[i * 4 + 3] = x4.w;
                        }
                        xt = xr[1024];
                    } else {
#pragma unroll
                        for (int i = 0; i < 4; i++)
#pragma unroll
                            for (int m = 0; m < 4; m++) {
                                int k = i * 256 + lane * 4 + m;
                                x[i * 4 + m] = (k < 1023) ? xr[1025 + k] : fsv;
                            }
                        xt = fev;
                    }
                }
#pragma unroll
                for (int gate = 0; gate < 3; gate++) {
                    int r = e * 3 + gate;
                    float s = 0.f;
#pragma unroll
                    for (int i = 0; i < 16; i++) s += w[r][i] * x[i];
#pragma unroll
                    for (int off = 32; off > 0; off >>= 1) s += __shfl_xor(s, off, 64);
                    v9[r] = s + wtail[r] * xt + bias9[r];
                }
            }
        };

        for (int t = 0; t < TP; t++) {
            // ---- flow control: may not lap the consumer (ring depth RS) ----
            if (t >= RS) {
                const int need = t - (RS - 1);
                while (true) {
                    ull c0 = ALOAD(flow0);
                    ull c1 = ALOAD(flow1);
                    int m0 = (int)(unsigned)(c0 >> 32);
                    int m1 = (int)(unsigned)(c1 >> 32);
                    if ((m0 > m1 ? m0 : m1) >= need) break;
                    __builtin_amdgcn_s_sleep(1);
                }
            }
            const bool doq = (t < TQ);

            // ---- stage h0 rows into LDS (coalesced float4, 8 floats/thr) ---
            {
                const float4* s = (const float4*)(ep + (size_t)t * 2048);
                float4* d = (float4*)xrawP;
                d[tid * 2]     = s[tid * 2];
                d[tid * 2 + 1] = s[tid * 2 + 1];
                if (doq) {
                    const float4* sq = (const float4*)(eq + (size_t)t * 2048);
                    float4* dq = (float4*)xrawQ;
                    dq[tid * 2]     = sq[tid * 2];
                    dq[tid * 2 + 1] = sq[tid * 2 + 1];
                }
            }
            __syncthreads();

            const ull tg = ((ull)(unsigned)(t + 1)) << 32;
            {
                float vP[9];
                prodChain(xrawP, fs[t], fe[t], vP);
                if (lane == 0) {
                    ull* dst = ringP + (size_t)(t & (RS - 1)) * RST + (size_t)cb * 36 + wave * 9;
#pragma unroll
                    for (int r = 0; r < 9; r++)
                        ASTORE(&dst[r], tg | (ull)__float_as_uint(vP[r]));
                }
            }
            if (doq) {
                float vQ[9];
                prodChain(xrawQ, 0.f, 0.f, vQ);
                if (lane == 0) {
                    ull* dst = ringQ + (size_t)t * RST + (size_t)cb * 36 + wave * 9;
#pragma unroll
                    for (int r = 0; r < 9; r++)
                        ASTORE(&dst[r], tg | (ull)__float_as_uint(vQ[r]));
                }
            }
            __syncthreads();  // protect xraw before next stage
        }
        return;
    }

    // =======================================================================
    //                               SCAN PATH  (Round-1 body, gh from ring)
    // =======================================================================
    int sh0[3], sspec[3];
#pragma unroll
    for (int e = 0; e < 3; e++) {
        sh0[e]   = __builtin_amdgcn_readfirstlane(dre[e] ? (1025 + je[e]) : je[e]);
        sspec[e] = __builtin_amdgcn_readfirstlane(
                       (dre[e] && je[e] >= 1023) ? (je[e] - 1022) : 0);
    }

    auto loadH0P = [&](int tt, float h03[3]) {
#pragma unroll
        for (int e = 0; e < 3; e++)
            h03[e] = (sspec[e] == 0) ? ep[(size_t)tt * 2048 + sh0[e]]
                   : (sspec[e] == 1) ? fs[tt] : fe[tt];
    };
    auto loadH0Q = [&](int tt, float h03[3]) {
#pragma unroll
        for (int e = 0; e < 3; e++)
            h03[e] = (sspec[e] == 0) ? eq[(size_t)tt * 2048 + sh0[e]] : 0.f;
    };

    const size_t rbase = (size_t)cb * 36 + (size_t)wave * 9;

    float ghcP[9], h0cP[3], ghcQ[9], h0cQ[3];
    // ---- initial gh for token 0 (expect tag 1; producers start instantly) --
    {
        ull v[9];
#pragma unroll
        for (int r = 0; r < 9; r++) v[r] = ALOAD(&ringP[rbase + r]);
        bool ok = false;
        while (!ok) {
            ok = true;
#pragma unroll
            for (int r = 0; r < 9; r++)
                if ((unsigned)(v[r] >> 32) != 1u) { ok = false; v[r] = ALOAD(&ringP[rbase + r]); }
        }
#pragma unroll
        for (int r = 0; r < 9; r++) ghcP[r] = __uint_as_float((unsigned)v[r]);

#pragma unroll
        for (int r = 0; r < 9; r++) v[r] = ALOAD(&ringQ[rbase + r]);
        ok = false;
        while (!ok) {
            ok = true;
#pragma unroll
            for (int r = 0; r < 9; r++)
                if ((unsigned)(v[r] >> 32) != 1u) { ok = false; v[r] = ALOAD(&ringQ[rbase + r]); }
        }
#pragma unroll
        for (int r = 0; r < 9; r++) ghcQ[r] = __uint_as_float((unsigned)v[r]);
    }
    loadH0P(0, h0cP);
    loadH0Q(0, h0cQ);

    ull* commP = comm;
    ull* commQ = comm + 2 * (size_t)GTOT;

    for (int t = 0; t < TP; t++) {
        const bool doq = (t < TQ);
        const int par = t & 1;

        // ================= gather y_{t-1} -> x (polls FIRST) ================
        if (t == 0) {
#pragma unroll
            for (int u = 0; u < 4; u++) {
                int j = tid + 256 * u;
                xsh[par][0][j] = 0.f;
                xsh[par][1][j] = 0.f;
            }
        } else {
            const int slot = (t + 1) & 1;     // (t-1) % 2
            const unsigned tag = (unsigned)t; // y_{t-1} carries tag t
            ull* cp = commP + slot * GTOT;
            ull* cq = commQ + slot * GTOT;
            int idx[8];
#pragma unroll
            for (int u = 0; u < 4; u++) {
                int j = tid + 256 * u;
                idx[2 * u]     = j;                              // yf[j]
                idx[2 * u + 1] = (j == 0) ? 1024 : (1024 + j);   // yb[j-1]
            }
            ull vp[8], vq[8];
#pragma unroll
            for (int u = 0; u < 8; u++) vp[u] = ALOAD(&cp[idx[u]]);
            if (doq) {
#pragma unroll
                for (int u = 0; u < 8; u++) vq[u] = ALOAD(&cq[idx[u]]);
            }
            bool done = false;
            while (!done) {
                done = true;
#pragma unroll
                for (int u = 0; u < 8; u++) {
                    if ((unsigned)(vp[u] >> 32) != tag) { done = false; vp[u] = ALOAD(&cp[idx[u]]); }
                }
                if (doq) {
#pragma unroll
                    for (int u = 0; u < 8; u++) {
                        if ((unsigned)(vq[u] >> 32) != tag) { done = false; vq[u] = ALOAD(&cq[idx[u]]); }
                    }
                }
            }
#pragma unroll
            for (int u = 0; u < 4; u++) {
                int j = tid + 256 * u;
                xsh[par][0][j] = __uint_as_float((unsigned)vp[2 * u]) +
                                 __uint_as_float((unsigned)vp[2 * u + 1]);
            }
            if (doq) {
#pragma unroll
                for (int u = 0; u < 4; u++) {
                    int j = tid + 256 * u;
                    xsh[par][1][j] = __uint_as_float((unsigned)vq[2 * u]) +
                                     __uint_as_float((unsigned)vq[2 * u + 1]);
                }
            }
        }

        // ==== issue ring prefetch for token t+1 (verified after publish) ====
        ull rp[9], rq[9];
        const bool ldn = (t + 1) < TP;
        const bool ldq = (t + 1) < TQ;
        const size_t rbP = (size_t)((t + 1) & (RS - 1)) * RST + rbase;
        const size_t rbQ = (size_t)(t + 1) * RST + rbase;
        if (ldn) {
#pragma unroll
            for (int r = 0; r < 9; r++) rp[r] = ALOAD(&ringP[rbP + r]);
        }
        if (ldq) {
#pragma unroll
            for (int r = 0; r < 9; r++) rq[r] = ALOAD(&ringQ[rbQ + r]);
        }
        __syncthreads();

        // ====== prefetch h0 for t+1 (hidden under dots) =====================
        float h0nP[3], h0nQ[3];
        if (ldn) loadH0P(t + 1, h0nP);
        if (ldq) loadH0Q(t + 1, h0nQ);

        // ========================= dot products =============================
        float accp[9];
        {
            float x[16];
#pragma unroll
            for (int i = 0; i < 4; i++) {
                float4 x4 = *(const float4*)&xsh[par][0][i * 256 + lane * 4];
                x[i * 4 + 0] = x4.x; x[i * 4 + 1] = x4.y;
                x[i * 4 + 2] = x4.z; x[i * 4 + 3] = x4.w;
            }
#pragma unroll
            for (int r = 0; r < 9; r++) {
                float s = 0.f;
#pragma unroll
                for (int i = 0; i < 16; i++) s += w[r][i] * x[i];
                accp[r] = s;
            }
        }
#pragma unroll
        for (int r = 0; r < 9; r++) {
            float v = accp[r];
#pragma unroll
            for (int off = 32; off > 0; off >>= 1) v += __shfl_xor(v, off, 64);
            accp[r] = v + bias9[r];
        }

        float accq[9];
        if (doq) {
            float x[16];
#pragma unroll
            for (int i = 0; i < 4; i++) {
                float4 x4 = *(const float4*)&xsh[par][1][i * 256 + lane * 4];
                x[i * 4 + 0] = x4.x; x[i * 4 + 1] = x4.y;
                x[i * 4 + 2] = x4.z; x[i * 4 + 3] = x4.w;
            }
#pragma unroll
            for (int r = 0; r < 9; r++) {
                float s = 0.f;
#pragma unroll
                for (int i = 0; i < 16; i++) s += w[r][i] * x[i];
#pragma unroll
                for (int off = 32; off > 0; off >>= 1) s += __shfl_xor(s, off, 64);
                accq[r] = s + bias9[r];
            }
        }

        // ================ gates; publish comm FIRST, out after ==============
        const ull tagout = ((ull)(unsigned)(t + 1)) << 32;
        float yP[3], yQ[3];
#pragma unroll
        for (int e = 0; e < 3; e++) {
            float r = sigm(accp[e * 3 + 0] + ghcP[e * 3 + 0]);
            float z = sigm(accp[e * 3 + 1] + ghcP[e * 3 + 1]);
            float n = fast_tanh(accp[e * 3 + 2] + r * ghcP[e * 3 + 2]);
            yP[e] = (1.f - z) * n + z * h0cP[e];
            if (lane == 0 && vale[e]) {
                ull pk = tagout | (ull)__float_as_uint(yP[e]);
                ASTORE(&commP[par * GTOT + (gbase + e)], pk);
            }
        }
        if (doq) {
#pragma unroll
            for (int e = 0; e < 3; e++) {
                float r = sigm(accq[e * 3 + 0] + ghcQ[e * 3 + 0]);
                float z = sigm(accq[e * 3 + 1] + ghcQ[e * 3 + 1]);
                float n = fast_tanh(accq[e * 3 + 2] + r * ghcQ[e * 3 + 2]);
                yQ[e] = (1.f - z) * n + z * h0cQ[e];
                if (lane == 0 && vale[e]) {
                    ull pk = tagout | (ull)__float_as_uint(yQ[e]);
                    ASTORE(&commQ[par * GTOT + (gbase + e)], pk);
                }
            }
        }
        // out stores (off the critical path)
        if (lane == 0) {
#pragma unroll
            for (int e = 0; e < 3; e++) {
                if (vale[e] && je[e] < H) {
                    out[(size_t)TQ * 2048 + (size_t)t * 2048 + dre[e] * H + je[e]] = yP[e];
                    if (doq)
                        out[(size_t)t * 2048 + dre[e] * H + je[e]] = yQ[e];
                }
            }
        }

        // ====== verify ring tags (rarely retries) and rotate into ghc =======
        if (ldn) {
            const unsigned expect = (unsigned)(t + 2);
            bool ok = false;
            while (!ok) {
                ok = true;
#pragma unroll
                for (int r = 0; r < 9; r++)
                    if ((unsigned)(rp[r] >> 32) != expect) { ok = false; rp[r] = ALOAD(&ringP[rbP + r]); }
            }
#pragma unroll
            for (int r = 0; r < 9; r++) ghcP[r] = __uint_as_float((unsigned)rp[r]);
#pragma unroll
            for (int e = 0; e < 3; e++) h0cP[e] = h0nP[e];
        }
        if (ldq) {
            const unsigned expect = (unsigned)(t + 2);
            bool ok = false;
            while (!ok) {
                ok = true;
#pragma unroll
                for (int r = 0; r < 9; r++)
                    if ((unsigned)(rq[r] >> 32) != expect) { ok = false; rq[r] = ALOAD(&ringQ[rbQ + r]); }
            }
#pragma unroll
            for (int r = 0; r < 9; r++) ghcQ[r] = __uint_as_float((unsigned)rq[r]);
#pragma unroll
            for (int e = 0; e < 3; e++) h0cQ[e] = h0nQ[e];
        }
    }
}

extern "C" void kernel_launch(void* const* d_in, const int* in_sizes, int n_in,
                              void* d_out, int out_size, void* d_ws, size_t ws_size,
                              hipStream_t stream) {
    const float* eq    = (const float*)d_in[0];
    const float* ep    = (const float*)d_in[1];
    const float* fs    = (const float*)d_in[2];
    const float* fe    = (const float*)d_in[3];
    const float* Wih_f = (const float*)d_in[4];
    const float* Whh_f = (const float*)d_in[5];
    const float* bih_f = (const float*)d_in[6];
    const float* bhh_f = (const float*)d_in[7];
    const float* Wih_b = (const float*)d_in[8];
    const float* Whh_b = (const float*)d_in[9];
    const float* bih_b = (const float*)d_in[10];
    const float* bhh_b = (const float*)d_in[11];
    float* out = (float*)d_out;

    ull* ringP = (ull*)d_ws;
    ull* ringQ = ringP + (size_t)RS * RST;
    ull* comm  = ringQ + (size_t)RS * RST;

    const size_t zeroBytes = ((size_t)2 * RS * RST + 4 * GTOT) * sizeof(ull);
    hipMemsetAsync(d_ws, 0, zeroBytes, stream);

    fused_bigru<<<dim3(NSCAN + NPROD), dim3(NTHR), 0, stream>>>(
        eq, ep, fs, fe, Wih_f, bih_f, Wih_b, bih_b,
        Whh_f, bhh_f, Whh_b, bhh_b, ringP, ringQ, comm, out);
}

// Round 5
// 14204.547 us; speedup vs baseline: 5.9431x; 3.2932x over previous
//
#include <hip/hip_runtime.h>
#include <stdint.h>

// BiGRU scan, H=1024. Round 6:
//  - Scan: byte-exact Round-1 kernel (171 blocks x 256 thr, launch_bounds(256,1),
//    204 VGPR, 12.89 ms steady). LESSON R2-R4: any other block shape or
//    launch-bounds second arg collapses the allocation to 128 VGPR and spills
//    the 144-float weight array (FETCH jumps from 0.6 GB to 8-31 GB). Do not
//    touch this configuration.
//  - gh GEMM: MFMA bf16-split version (A = Ah + Al bf16 split, W single bf16;
//    gh = Ah*W + Al*W). gh does not feed back through the recurrence, so the
//    ~1.3e-3 added error is absorbed (existing absmax 1.5e-2 from fast_tanh).
//    Replaces the ~1.4 ms fp32 vector GEMM with ~0.3 ms.

#define H   1024
#define HH  1025
#define N3  3075      // 3*HH
#define TQ  512
#define TP  4096
#define MTOT 4608     // TQ + TP rows in gh (q tokens first, then p tokens)
#define GTOT 2050     // 2 dirs * HH output elems per step
#define GH_ELEMS (MTOT * N3)   // 14,169,600 floats per dir

typedef unsigned long long ull;
typedef __attribute__((ext_vector_type(8))) short short8;
typedef __attribute__((ext_vector_type(4))) float f32x4;

__device__ __forceinline__ float sigm(float x) { return 1.f / (1.f + __expf(-x)); }
__device__ __forceinline__ float fast_tanh(float x) {
    float e = __expf(2.f * x);
    return (e - 1.f) / (e + 1.f);
}

__device__ __forceinline__ unsigned short f2bf(float f) {
    unsigned u = __float_as_uint(f);
    unsigned r = (u + 0x7FFFu + ((u >> 16) & 1u)) >> 16;
    return (unsigned short)r;
}
__device__ __forceinline__ float bf2f(unsigned short h) {
    return __uint_as_float(((unsigned)h) << 16);
}

// ---------------------------------------------------------------------------
// MFMA gh GEMM: gh[dir][m][r] = sum_k h0[m][dir][k] * Whh_dir[r][k] + bhh[r]
// Block tile 64(M) x 128(N), K-chunks of 32 (33 chunks, zero-padded).
// Wave w owns rows 16w..16w+15; 8 column tiles of 16; acc = 8 x f32x4.
// A split to bf16 hi+lo in LDS; B single bf16. Row stride 40 halfwords (80 B)
// keeps ds_read_b128 bank aliasing at 2-way (free).
// ---------------------------------------------------------------------------
__global__ __launch_bounds__(256, 2) void gh_gemm_mfma(
    const float* __restrict__ eq, const float* __restrict__ ep,
    const float* __restrict__ fs, const float* __restrict__ fe,
    const float* __restrict__ Whh_f, const float* __restrict__ bhh_f,
    const float* __restrict__ Whh_b, const float* __restrict__ bhh_b,
    float* __restrict__ ghf, float* __restrict__ ghb)
{
    const int dir = blockIdx.z;
    const float* W  = dir ? Whh_b : Whh_f;
    const float* bh = dir ? bhh_b : bhh_f;
    float* gh = dir ? ghb : ghf;
    const int n0 = blockIdx.x * 128;
    const int m0 = blockIdx.y * 64;
    const int tid  = threadIdx.x;
    const int wave = tid >> 6;
    const int lane = tid & 63;

    __shared__ __align__(16) unsigned short Ah[64][40];
    __shared__ __align__(16) unsigned short Al[64][40];
    __shared__ __align__(16) unsigned short Bs[128][40];

    f32x4 acc[8];
#pragma unroll
    for (int c = 0; c < 8; c++) acc[c] = (f32x4){0.f, 0.f, 0.f, 0.f};

    for (int kc = 0; kc < 33; kc++) {
        const int k0 = kc * 32;
        // ---- stage A (64 rows x 32 k), gather + bf16 hi/lo split ----
#pragma unroll
        for (int u = 0; u < 8; u++) {
            int lin = u * 256 + tid;
            int row = lin >> 5, k = lin & 31;
            int gm = m0 + row, gk = k0 + k;
            float v = 0.f;
            if (gk < HH) {
                bool isq = gm < TQ;
                const float* e = isq ? eq : ep;
                int t = isq ? gm : gm - TQ;
                if (dir == 0)            v = e[(size_t)t * 2048 + gk];
                else if (gk < 1023)      v = e[(size_t)t * 2048 + 1025 + gk];
                else if (!isq)           v = (gk == 1023) ? fs[t] : fe[t];
            }
            unsigned short h = f2bf(v);
            Ah[row][k] = h;
            Al[row][k] = f2bf(v - bf2f(h));
        }
        // ---- stage B (128 rows x 32 k), single bf16 ----
#pragma unroll
        for (int u = 0; u < 16; u++) {
            int lin = u * 256 + tid;
            int r = lin >> 5, k = lin & 31;
            int gr = n0 + r, gk = k0 + k;
            float v = (gr < N3 && gk < HH) ? W[(size_t)gr * HH + gk] : 0.f;
            Bs[r][k] = f2bf(v);
        }
        __syncthreads();

        // ---- MFMA: lane l holds row R+(l&15), k-halfwords (l>>4)*8..+8 ----
        const int arow = wave * 16 + (lane & 15);
        const int koff = (lane >> 4) * 8;
        short8 ah = *(const short8*)&Ah[arow][koff];
        short8 al = *(const short8*)&Al[arow][koff];
#pragma unroll
        for (int c = 0; c < 8; c++) {
            short8 b = *(const short8*)&Bs[c * 16 + (lane & 15)][koff];
            acc[c] = __builtin_amdgcn_mfma_f32_16x16x32_bf16(ah, b, acc[c], 0, 0, 0);
            acc[c] = __builtin_amdgcn_mfma_f32_16x16x32_bf16(al, b, acc[c], 0, 0, 0);
        }
        __syncthreads();
    }

    // ---- epilogue: C/D layout col=lane&15, row=(lane>>4)*4+reg (m89) ----
#pragma unroll
    for (int c = 0; c < 8; c++) {
        int col = n0 + c * 16 + (lane & 15);
        if (col < N3) {
            float bias = bh[col];
#pragma unroll
            for (int r = 0; r < 4; r++) {
                int row = m0 + wave * 16 + (lane >> 4) * 4 + r;
                gh[(size_t)row * N3 + col] = acc[c][r] + bias;
            }
        }
    }
}

// ---------------------------------------------------------------------------
// Persistent scan. 171 blocks x 256 threads; wave w of block b owns output
// elems g = b*12 + w*3 + {0,1,2}. Lane l holds Wih[row][4l + 256i + m].
// BYTE-EXACT Round-1 kernel (204 VGPR, 12.89 ms steady). Do not modify.
// ---------------------------------------------------------------------------
__global__ __launch_bounds__(256, 1) void bigru_scan(
    const float* __restrict__ eq, const float* __restrict__ ep,
    const float* __restrict__ fs, const float* __restrict__ fe,
    const float* __restrict__ Wih_f, const float* __restrict__ bih_f,
    const float* __restrict__ Wih_b, const float* __restrict__ bih_b,
    const float* __restrict__ ghf, const float* __restrict__ ghb,
    ull* __restrict__ comm,   // [chain p|q][slot 0|1][GTOT] tagged values
    float* __restrict__ out)  // h_q (512*2048) then h_p (4096*2048)
{
    __shared__ float xsh[2][2][1024];  // [parity][chain p=0,q=1][j]

    const int tid  = threadIdx.x;
    const int wave = tid >> 6;
    const int lane = tid & 63;
    const int gbase = blockIdx.x * 12 + wave * 3;

    // ---- register-resident weights ----
    float wreg[9][16];
    float breg[9];
    int   dre[3], je[3];
    bool  vale[3];
#pragma unroll
    for (int e = 0; e < 3; e++) {
        int g = gbase + e;
        bool v = (g < GTOT);
        int gc = v ? g : 0;
        int dir = gc / HH;
        int j = gc % HH;
        dre[e] = dir; je[e] = j; vale[e] = v;
        const float* Wih = dir ? Wih_b : Wih_f;
        const float* bih = dir ? bih_b : bih_f;
#pragma unroll
        for (int gate = 0; gate < 3; gate++) {
            const float* wr = Wih + (size_t)(gate * HH + j) * H;
#pragma unroll
            for (int i = 0; i < 4; i++) {
                float4 w4 = *(const float4*)(wr + i * 256 + lane * 4);
                wreg[e * 3 + gate][i * 4 + 0] = w4.x;
                wreg[e * 3 + gate][i * 4 + 1] = w4.y;
                wreg[e * 3 + gate][i * 4 + 2] = w4.z;
                wreg[e * 3 + gate][i * 4 + 3] = w4.w;
            }
            breg[e * 3 + gate] = bih[gate * HH + j];
        }
    }

    // ---- scalarized (wave-uniform) per-e offsets for the gh/h0 pipeline ----
    int sgh[3], sh0[3], sspec[3];
#pragma unroll
    for (int e = 0; e < 3; e++) {
        sgh[e]   = __builtin_amdgcn_readfirstlane(dre[e] * GH_ELEMS + je[e]);
        sh0[e]   = __builtin_amdgcn_readfirstlane(dre[e] ? (1025 + je[e]) : je[e]);
        sspec[e] = __builtin_amdgcn_readfirstlane(
                       (dre[e] && je[e] >= 1023) ? (je[e] - 1022) : 0);
    }
    const float* ghAll = ghf;  // ghb is contiguous at ghf + GH_ELEMS

    // ---- gh/h0 register pipeline (one step ahead) ----
    float ghcP[9], h0cP[3], ghcQ[9], h0cQ[3];

    auto loadP = [&](int tt, float gh9[9], float h03[3]) {
        size_t base = (size_t)(TQ + tt) * N3;
#pragma unroll
        for (int e = 0; e < 3; e++) {
#pragma unroll
            for (int gate = 0; gate < 3; gate++)
                gh9[e * 3 + gate] = ghAll[base + (size_t)sgh[e] + gate * HH];
            h03[e] = (sspec[e] == 0) ? ep[(size_t)tt * 2048 + sh0[e]]
                   : (sspec[e] == 1) ? fs[tt] : fe[tt];
        }
    };
    auto loadQ = [&](int tt, float gh9[9], float h03[3]) {
        size_t base = (size_t)tt * N3;
#pragma unroll
        for (int e = 0; e < 3; e++) {
#pragma unroll
            for (int gate = 0; gate < 3; gate++)
                gh9[e * 3 + gate] = ghAll[base + (size_t)sgh[e] + gate * HH];
            h03[e] = (sspec[e] == 0) ? eq[(size_t)tt * 2048 + sh0[e]] : 0.f;
        }
    };

    loadP(0, ghcP, h0cP);
    loadQ(0, ghcQ, h0cQ);

    ull* commP = comm;
    ull* commQ = comm + 2 * GTOT;

    for (int t = 0; t < TP; t++) {
        const bool doq = (t < TQ);
        const int par = t & 1;

        // ================= gather y_{t-1} -> x (polls FIRST) ================
        if (t == 0) {
#pragma unroll
            for (int u = 0; u < 4; u++) {
                int j = tid + 256 * u;
                xsh[par][0][j] = 0.f;
                xsh[par][1][j] = 0.f;
            }
        } else {
            const int slot = (t + 1) & 1;     // (t-1) % 2
            const unsigned tag = (unsigned)t; // y_{t-1} carries tag t
            ull* cp = commP + slot * GTOT;
            ull* cq = commQ + slot * GTOT;
            int idx[8];
#pragma unroll
            for (int u = 0; u < 4; u++) {
                int j = tid + 256 * u;
                idx[2 * u]     = j;                                // yf[j]
                idx[2 * u + 1] = (j == 0) ? 1024 : (1025 + j - 1); // yb[j-1]
            }
            ull vp[8], vq[8];
#pragma unroll
            for (int u = 0; u < 8; u++)
                vp[u] = __hip_atomic_load(&cp[idx[u]], __ATOMIC_RELAXED, __HIP_MEMORY_SCOPE_AGENT);
            if (doq) {
#pragma unroll
                for (int u = 0; u < 8; u++)
                    vq[u] = __hip_atomic_load(&cq[idx[u]], __ATOMIC_RELAXED, __HIP_MEMORY_SCOPE_AGENT);
            }
            // batch retry: one LLC latency per round, p+q overlapped
            bool done = false;
            while (!done) {
                done = true;
#pragma unroll
                for (int u = 0; u < 8; u++) {
                    if ((unsigned)(vp[u] >> 32) != tag) {
                        done = false;
                        vp[u] = __hip_atomic_load(&cp[idx[u]], __ATOMIC_RELAXED, __HIP_MEMORY_SCOPE_AGENT);
                    }
                }
                if (doq) {
#pragma unroll
                    for (int u = 0; u < 8; u++) {
                        if ((unsigned)(vq[u] >> 32) != tag) {
                            done = false;
                            vq[u] = __hip_atomic_load(&cq[idx[u]], __ATOMIC_RELAXED, __HIP_MEMORY_SCOPE_AGENT);
                        }
                    }
                }
            }
#pragma unroll
            for (int u = 0; u < 4; u++) {
                int j = tid + 256 * u;
                xsh[par][0][j] = __uint_as_float((unsigned)vp[2 * u]) +
                                 __uint_as_float((unsigned)vp[2 * u + 1]);
            }
            if (doq) {
#pragma unroll
                for (int u = 0; u < 4; u++) {
                    int j = tid + 256 * u;
                    xsh[par][1][j] = __uint_as_float((unsigned)vq[2 * u]) +
                                     __uint_as_float((unsigned)vq[2 * u + 1]);
                }
            }
        }
        __syncthreads();

        // ====== prefetch gh/h0 for t+1 (scalar path; hidden under dots) =====
        float ghnP[9], h0nP[3], ghnQ[9], h0nQ[3];
        const bool ldn = (t + 1) < TP;
        const bool ldq = (t + 1) < TQ;
        if (ldn) loadP(t + 1, ghnP, h0nP);
        if (ldq) loadQ(t + 1, ghnQ, h0nQ);

        // ========================= dot products =============================
        float accp[9];
        {
            float x[16];
#pragma unroll
            for (int i = 0; i < 4; i++) {
                float4 x4 = *(const float4*)&xsh[par][0][i * 256 + lane * 4];
                x[i * 4 + 0] = x4.x; x[i * 4 + 1] = x4.y;
                x[i * 4 + 2] = x4.z; x[i * 4 + 3] = x4.w;
            }
#pragma unroll
            for (int r = 0; r < 9; r++) {
                float s = 0.f;
#pragma unroll
                for (int i = 0; i < 16; i++) s += wreg[r][i] * x[i];
                accp[r] = s;
            }
        }
#pragma unroll
        for (int r = 0; r < 9; r++) {
            float v = accp[r];
#pragma unroll
            for (int off = 32; off > 0; off >>= 1) v += __shfl_xor(v, off, 64);
            accp[r] = v + breg[r];
        }

        float accq[9];
        if (doq) {
            float x[16];
#pragma unroll
            for (int i = 0; i < 4; i++) {
                float4 x4 = *(const float4*)&xsh[par][1][i * 256 + lane * 4];
                x[i * 4 + 0] = x4.x; x[i * 4 + 1] = x4.y;
                x[i * 4 + 2] = x4.z; x[i * 4 + 3] = x4.w;
            }
#pragma unroll
            for (int r = 0; r < 9; r++) {
                float s = 0.f;
#pragma unroll
                for (int i = 0; i < 16; i++) s += wreg[r][i] * x[i];
#pragma unroll
                for (int off = 32; off > 0; off >>= 1) s += __shfl_xor(s, off, 64);
                accq[r] = s + breg[r];
            }
        }

        // ================ gates; publish comm FIRST, out after ==============
        const ull tagout = ((ull)(unsigned)(t + 1)) << 32;
        float yP[3], yQ[3];
#pragma unroll
        for (int e = 0; e < 3; e++) {
            float r = sigm(accp[e * 3 + 0] + ghcP[e * 3 + 0]);
            float z = sigm(accp[e * 3 + 1] + ghcP[e * 3 + 1]);
            float n = fast_tanh(accp[e * 3 + 2] + r * ghcP[e * 3 + 2]);
            yP[e] = (1.f - z) * n + z * h0cP[e];
            if (lane == 0 && vale[e]) {
                ull pk = tagout | (ull)__float_as_uint(yP[e]);
                __hip_atomic_store(&commP[par * GTOT + (gbase + e)], pk,
                                   __ATOMIC_RELAXED, __HIP_MEMORY_SCOPE_AGENT);
            }
        }
        if (doq) {
#pragma unroll
            for (int e = 0; e < 3; e++) {
                float r = sigm(accq[e * 3 + 0] + ghcQ[e * 3 + 0]);
                float z = sigm(accq[e * 3 + 1] + ghcQ[e * 3 + 1]);
                float n = fast_tanh(accq[e * 3 + 2] + r * ghcQ[e * 3 + 2]);
                yQ[e] = (1.f - z) * n + z * h0cQ[e];
                if (lane == 0 && vale[e]) {
                    ull pk = tagout | (ull)__float_as_uint(yQ[e]);
                    __hip_atomic_store(&commQ[par * GTOT + (gbase + e)], pk,
                                       __ATOMIC_RELAXED, __HIP_MEMORY_SCOPE_AGENT);
                }
            }
        }
        // out stores (off the critical path)
        if (lane == 0) {
#pragma unroll
            for (int e = 0; e < 3; e++) {
                if (vale[e] && je[e] < H) {
                    out[(size_t)TQ * 2048 + (size_t)t * 2048 + dre[e] * H + je[e]] = yP[e];
                    if (doq)
                        out[(size_t)t * 2048 + dre[e] * H + je[e]] = yQ[e];
                }
            }
        }

        // rotate pipeline registers
        if (ldn) {
#pragma unroll
            for (int i = 0; i < 9; i++) ghcP[i] = ghnP[i];
#pragma unroll
            for (int e = 0; e < 3; e++) h0cP[e] = h0nP[e];
        }
        if (ldq) {
#pragma unroll
            for (int i = 0; i < 9; i++) ghcQ[i] = ghnQ[i];
#pragma unroll
            for (int e = 0; e < 3; e++) h0cQ[e] = h0nQ[e];
        }
    }
}

extern "C" void kernel_launch(void* const* d_in, const int* in_sizes, int n_in,
                              void* d_out, int out_size, void* d_ws, size_t ws_size,
                              hipStream_t stream) {
    const float* eq    = (const float*)d_in[0];
    const float* ep    = (const float*)d_in[1];
    const float* fs    = (const float*)d_in[2];
    const float* fe    = (const float*)d_in[3];
    const float* Wih_f = (const float*)d_in[4];
    const float* Whh_f = (const float*)d_in[5];
    const float* bih_f = (const float*)d_in[6];
    const float* bhh_f = (const float*)d_in[7];
    const float* Wih_b = (const float*)d_in[8];
    const float* Whh_b = (const float*)d_in[9];
    const float* bih_b = (const float*)d_in[10];
    const float* bhh_b = (const float*)d_in[11];
    float* out = (float*)d_out;

    const size_t ghElems = (size_t)GH_ELEMS;
    float* ghf = (float*)d_ws;
    float* ghb = ghf + ghElems;
    size_t commOff = ((2 * ghElems * sizeof(float)) + 4095) & ~(size_t)4095;
    ull* comm = (ull*)((char*)d_ws + commOff);

    hipMemsetAsync(comm, 0, (size_t)4 * GTOT * sizeof(ull), stream);

    dim3 ggrid((N3 + 127) / 128, MTOT / 64, 2);
    gh_gemm_mfma<<<ggrid, 256, 0, stream>>>(eq, ep, fs, fe, Whh_f, bhh_f, Whh_b, bhh_b, ghf, ghb);

    bigru_scan<<<dim3(171), dim3(256), 0, stream>>>(
        eq, ep, fs, fe, Wih_f, bih_f, Wih_b, bih_b, ghf, ghb, comm, out);
}